// Round 6
// baseline (2157.235 us; speedup 1.0000x reference)
//
#include <hip/hip_runtime.h>

// Shapes: BS=256, C=256, H=W=16, HW=256, conv1: 1024->1024 3x3, conv2: 1024->512 3x3,
// cls: 512->512 1x1 (only diagonal of PSROI needed -> 2 dots/pixel).
//
// Workspace layout (bytes):
//   featT  @ 0          : bf16 [256 b][256 p][1024 ch]  = 134217728   (ch: r1|corr1|r2|corr2)
//   out1T  @ 134217728  : bf16 [256 b][256 p][1024 o]   = 134217728
//   W1b    @ 268435456  : bf16 [9][1024][1024]          = 18874368
//   W2b    @ 287309824  : bf16 [9][512][1024]           = 9437184
//   s1     @ 296747008  : f32  [256*256]                = 262144
//   s2     @ 297009152  : f32  [256*256]                = 262144
//   out2T  @ 0 (overlays featT, dead after conv1): bf16 [256][256][512] = 67108864
//
// SWIZZLED STORAGE FORMAT: every bf16 row-major tensor stores each 64B slice
// (4 x 16B chunks) with chunk index XORed by ((row>>1)&3), row = pixel p or
// out-channel o. Conflict-light LDS b128 reads with monotonic gl2lds staging;
// conv epilogue emits merged uint4 stores (full-line write combine).
//
// r6 conv: r4 geometry (512 thr, 8 waves of 64x64, 16x16x32 MFMA) + REGISTER
// FRAGMENT PIPELINE. r4/r5 PMC showed MFMA ~60% AND LDS ~60% with neither
// saturated -> per-step {barrier, ds_read, MFMA, barrier} serialization loss.
// Now: at step s, issue W(s+3) (depth-3, 3 bufs, buf = tap%3), ds_read frags
// for step s+1 (bufs published at barrier(s-1)), MFMA step s from registers.
// Waits: lgkmcnt(0) + vmcnt(3|1) pre-barrier (FIFO audited; W(k) lands end of
// step k-2, read at k-1). 1 block/CU (VGPR ~170), launch_bounds(512,2).

typedef __attribute__((ext_vector_type(8))) __bf16 bf16x8;
typedef __attribute__((ext_vector_type(4))) float f32x4;
typedef unsigned short u16;

template <bool B> struct BC { static constexpr bool value = B; };

__device__ __forceinline__ u16 f2bf(float f) {
  union { float f; unsigned u; } v; v.f = f;
  unsigned u = v.u;
  u += 0x7fffu + ((u >> 16) & 1u);   // RNE
  return (u16)(u >> 16);
}
__device__ __forceinline__ float bf2f(u16 h) {
  union { unsigned u; float f; } v; v.u = ((unsigned)h) << 16;
  return v.f;
}
__device__ __forceinline__ void gl2lds16(const void* g, void* l) {
  __builtin_amdgcn_global_load_lds(
      (__attribute__((address_space(1))) void*)(void*)g,
      (__attribute__((address_space(3))) void*)l, 16, 0, 0);
}

// ---------------------------------------------------------------------------
// Kernel 1: relu + channel-L2-norm scales + bf16 transpose to featT[b][p][ch].
// Stores in swizzled format: ch' = ch ^ (((p>>1)&3)<<3).
__global__ __launch_bounds__(256) void k_norm(const float* __restrict__ f1,
                                              const float* __restrict__ f2,
                                              u16* __restrict__ featT,
                                              float* __restrict__ s1,
                                              float* __restrict__ s2) {
  int bx = blockIdx.x;
  int b = bx >> 2;
  int p0 = (bx & 3) << 6;
  int t = threadIdx.x;
  int p = p0 + (t & 63);
  int cg = t >> 6;
  int sp3 = ((p >> 1) & 3) << 3;
  const float* F1 = f1 + ((size_t)b << 16);
  const float* F2 = f2 + ((size_t)b << 16);
  u16* FT = featT + (((size_t)(b << 8) + p) << 10);
  float ss1 = 0.f, ss2 = 0.f;
  for (int i = 0; i < 64; ++i) {
    int c = (cg << 6) + i;
    float v1 = F1[(c << 8) + p]; v1 = v1 > 0.f ? v1 : 0.f;
    float v2 = F2[(c << 8) + p]; v2 = v2 > 0.f ? v2 : 0.f;
    ss1 += v1 * v1; ss2 += v2 * v2;
    FT[c ^ sp3] = f2bf(v1);
    FT[512 + (c ^ sp3)] = f2bf(v2);
  }
  __shared__ float l1[256], l2[256];
  l1[t] = ss1; l2[t] = ss2;
  __syncthreads();
  if (t < 64) {
    float a = l1[t] + l1[t + 64] + l1[t + 128] + l1[t + 192];
    float c2 = l2[t] + l2[t + 64] + l2[t + 128] + l2[t + 192];
    int pp = (b << 8) + p0 + t;
    s1[pp] = 1.f / fmaxf(sqrtf(a), 1e-12f);
    s2[pp] = 1.f / fmaxf(sqrtf(c2), 1e-12f);
  }
}

// ---------------------------------------------------------------------------
// Kernel 2: weight repack fp32 [O][C][3][3] -> bf16 [tap][O][C], swizzled:
// c' = c ^ (((o>>1)&3)<<3).
__global__ __launch_bounds__(256) void k_wconv(const float* __restrict__ w,
                                               u16* __restrict__ wb, int O, int C) {
  int o = blockIdx.x;
  int t = threadIdx.x;
  int sp3 = ((o >> 1) & 3) << 3;
  const float* src = w + (size_t)o * C * 9;
  for (int c = t; c < C; c += 256) {
    const float* s = src + c * 9;
    float v[9];
#pragma unroll
    for (int i = 0; i < 9; ++i) v[i] = s[i];
#pragma unroll
    for (int tap = 0; tap < 9; ++tap)
      wb[(size_t)tap * O * C + (size_t)o * C + (c ^ sp3)] = f2bf(v[tap]);
  }
}

// ---------------------------------------------------------------------------
// Kernel 3: Gram GEMM G[p1][p2] = sum_c r1[p1][c]*r2[p2][c], scaled epilogue.
// (unchanged r4: 16x16x32 MFMA, monotonic staging, swizzled read chunk)
__global__ __launch_bounds__(256) void k_corr(u16* featT,
                                              const float* __restrict__ s1,
                                              const float* __restrict__ s2,
                                              float* __restrict__ out) {
  __shared__ alignas(16) u16 Alds[128 * 32];
  __shared__ alignas(16) u16 Blds[128 * 32];
  __shared__ float tb[4][16][66];
  int bx = blockIdx.x;
  int b = bx >> 2;
  int p1b = ((bx >> 1) & 1) << 7;
  int p2b = (bx & 1) << 7;
  int t = threadIdx.x, l = t & 63, w = t >> 6;
  int wm = w >> 1, wn = w & 1, lr = l & 15, lq = l >> 4;
  int srow = (w << 4) + (l >> 2);
  int sq = (l & 3) << 3;                       // monotonic source chunk
  int rsz = ((lq ^ ((lr >> 1) & 3)) << 3);     // swizzled read chunk
  const size_t bbase = (size_t)b << 18;

  f32x4 acc[4][4];
#pragma unroll
  for (int i = 0; i < 4; ++i)
#pragma unroll
    for (int j = 0; j < 4; ++j) acc[i][j] = (f32x4){0.f, 0.f, 0.f, 0.f};

#pragma unroll 1
  for (int kc = 0; kc < 8; ++kc) {
    int c0 = kc << 5;
    const u16* sA = featT + bbase + ((size_t)(p1b + srow) << 10) + (c0 + sq);
    gl2lds16(sA, Alds + ((w << 4) << 5));
    gl2lds16(sA + (64 << 10), Alds + ((64 + (w << 4)) << 5));
    const u16* sB = featT + bbase + ((size_t)(p2b + srow) << 10) + (512 + c0 + sq);
    gl2lds16(sB, Blds + ((w << 4) << 5));
    gl2lds16(sB + (64 << 10), Blds + ((64 + (w << 4)) << 5));
    __syncthreads();
    bf16x8 af[4], bfr[4];
#pragma unroll
    for (int mf = 0; mf < 4; ++mf)
      af[mf] = *(const bf16x8*)(Alds + (((wm << 6) + (mf << 4) + lr) << 5) + rsz);
#pragma unroll
    for (int nf = 0; nf < 4; ++nf)
      bfr[nf] = *(const bf16x8*)(Blds + (((wn << 6) + (nf << 4) + lr) << 5) + rsz);
#pragma unroll
    for (int mf = 0; mf < 4; ++mf)
#pragma unroll
      for (int nf = 0; nf < 4; ++nf)
        acc[mf][nf] = __builtin_amdgcn_mfma_f32_16x16x32_bf16(af[mf], bfr[nf], acc[mf][nf], 0, 0, 0);
    __syncthreads();
  }

  float sc2[4]; int p2g[4];
#pragma unroll
  for (int nf = 0; nf < 4; ++nf) {
    int p2 = p2b + (wn << 6) + (nf << 4) + lr;
    p2g[nf] = p2;
    sc2[nf] = s2[(b << 8) + p2];
  }
  float* corr1 = out + 512;
  float* corr2 = out + 512 + 16777216;
#pragma unroll
  for (int mf = 0; mf < 4; ++mf) {
    float gv[4][4];
#pragma unroll
    for (int r = 0; r < 4; ++r) {
      int p1 = p1b + (wm << 6) + (mf << 4) + (lq << 2) + r;
      float s1v = s1[(b << 8) + p1];
#pragma unroll
      for (int nf = 0; nf < 4; ++nf) gv[nf][r] = acc[mf][nf][r] * s1v * sc2[nf];
    }
#pragma unroll
    for (int r = 0; r < 4; ++r) {
      int p1 = p1b + (wm << 6) + (mf << 4) + (lq << 2) + r;
      int s1p3 = ((p1 >> 1) & 3) << 3;
#pragma unroll
      for (int nf = 0; nf < 4; ++nf) {
        corr2[((size_t)b << 16) + ((size_t)p1 << 8) + p2g[nf]] = gv[nf][r];
        featT[bbase + ((size_t)p1 << 10) + 256 + (p2g[nf] ^ s1p3)] = f2bf(gv[nf][r]);
      }
    }
#pragma unroll
    for (int r = 0; r < 4; ++r)
#pragma unroll
      for (int nf = 0; nf < 4; ++nf)
        tb[w][(lq << 2) + r][(nf << 4) + lr] = gv[nf][r];
#pragma unroll
    for (int j = 0; j < 16; ++j) {
      float v = tb[w][lr][(j << 2) + lq];
      int p2 = p2b + (wn << 6) + (j << 2) + lq;
      int s2p3 = ((p2 >> 1) & 3) << 3;
      int p1 = p1b + (wm << 6) + (mf << 4) + lr;
      corr1[((size_t)b << 16) + ((size_t)p2 << 8) + p1] = v;
      featT[bbase + ((size_t)p2 << 10) + 768 + (p1 ^ s2p3)] = f2bf(v);
    }
  }
}

// ---------------------------------------------------------------------------
// Kernel 4/5: implicit-GEMM 3x3 conv with register fragment pipeline.
// Block = whole image M=256 x N=128 o, 512 threads = 8 waves (4M x 2N) 64x64.
// Step s = (kc,tap): issue W(s+3) -> Wlds[tap%3]; ds_read frags(s+1) from
// Wlds[(tap+1)%3] / X parity buf; MFMA frags(s) from regs. X(kc+1) staged at
// tap0 (drained end of tap2, read for prefetch at tap8). Pre-barrier:
// lgkmcnt(0) (WAR safety for frag reads) + vmcnt(3 @taps 0-1, 1 @taps 2-8).
// Epilogue: per-wave LDS transpose -> merged uint4 stores in swizzled format.
template <int O, int OTB>
__global__ __launch_bounds__(512, 2) void k_conv(const u16* __restrict__ X,
                                                 const u16* __restrict__ Wb,
                                                 const float* __restrict__ bias,
                                                 u16* __restrict__ Out) {
  __shared__ alignas(16) u16 Xlds[2][260 * 32];  // rows 0..255 data, row 256 = zeros
  __shared__ alignas(16) u16 Wlds[3][128 * 32];
  int bx = blockIdx.x;
  int otile = bx & ((1 << OTB) - 1);   // low bits -> XCD affinity for the W slice
  int b = bx >> OTB;
  int t = threadIdx.x, l = t & 63, w = t >> 6;
  int wm = w & 3, wn = w >> 2;
  int lr = l & 15, lq = l >> 4;
  int o0 = otile << 7;
  int srl = l >> 2;
  int sq = (l & 3) << 3;               // monotonic source chunk
  const size_t xbase = (size_t)b << 18;

  const u16* wsrc = Wb + (((size_t)(o0 + (w << 4) + srl)) << 10) + sq;
  const u16* xsrc0 = X + xbase + (((size_t)((w << 4) + srl)) << 10) + sq;
  const u16* xsrc1 = xsrc0 + ((size_t)128 << 10);

  u16* wdst0 = &Wlds[0][(w << 4) << 5];
  u16* wdst1 = &Wlds[1][(w << 4) << 5];
  u16* wdst2 = &Wlds[2][(w << 4) << 5];
  u16* xdA0 = &Xlds[0][(w << 4) << 5];
  u16* xdA1 = &Xlds[0][(128 + (w << 4)) << 5];
  u16* xdB0 = &Xlds[1][(w << 4) << 5];
  u16* xdB1 = &Xlds[1][(128 + (w << 4)) << 5];

  // W read: row = (wn<<6)+(nf<<4)+lr -> stored swizzle ((row>>1)&3) == ((lr>>1)&3).
  int rszw = ((lq ^ ((lr >> 1) & 3)) << 3);
  const u16* bwb0 = &Wlds[0][(((wn << 6) + lr) << 5) + rszw];
  const u16* bwb1 = &Wlds[1][(((wn << 6) + lr) << 5) + rszw];
  const u16* bwb2 = &Wlds[2][(((wn << 6) + lr) << 5) + rszw];

  // X read swizzle variants indexed by dc (storage keyed on row = pixel).
  int pb[4];
#pragma unroll
  for (int mf = 0; mf < 4; ++mf)
    pb[mf] = (((wm << 6) + (mf << 4) + lr) << 5);
  int xsz[3];
#pragma unroll
  for (int d = 0; d < 3; ++d)
    xsz[d] = ((lq ^ (((lr + d - 1) >> 1) & 3)) << 3);
  const int zoff = (256 << 5) + (lq << 3);   // zero row

  f32x4 acc[4][4];
#pragma unroll
  for (int i = 0; i < 4; ++i)
#pragma unroll
    for (int j = 0; j < 4; ++j) acc[i][j] = (f32x4){0.f, 0.f, 0.f, 0.f};

  bf16x8 fa[2][4], fw[2][4];   // ping-pong fragment registers (static indexing)

  if (t < 32) ((unsigned*)&Xlds[t >> 4][256 << 5])[t & 15] = 0u;

  // prologue: X(0) -> Xbuf0; W(0),W(1),W(2) -> bufs 0,1,2
  gl2lds16(xsrc0, xdA0);
  gl2lds16(xsrc1, xdA1);
  gl2lds16(wsrc, wdst0);
  gl2lds16(wsrc + ((size_t)O << 10), wdst1);
  gl2lds16(wsrc + 2 * ((size_t)O << 10), wdst2);
  // drain X, W0, W1 (keep W2 in flight); drain zero-row ds_write
  asm volatile("s_waitcnt vmcnt(1) lgkmcnt(0)" ::: "memory");
  __builtin_amdgcn_s_barrier();
  // read frags(0): tap0 (dr=-1,dc=-1), Xbuf0, Wbuf0
  {
#pragma unroll
    for (int nf = 0; nf < 4; ++nf) fw[0][nf] = *(const bf16x8*)(bwb0 + (nf << 9));
    const int pdpo = ((-17) << 5) + xsz[0];
#pragma unroll
    for (int mf = 0; mf < 4; ++mf) {
      int rr = (wm << 2) + mf - 1;
      bool v = ((unsigned)rr < 16u) & ((unsigned)(lr - 1) < 16u);
      int off = v ? (pb[mf] + pdpo) : zoff;
      fa[0][mf] = *(const bf16x8*)(&Xlds[0][0] + off);
    }
  }
  asm volatile("s_waitcnt lgkmcnt(0)" ::: "memory");
  __builtin_amdgcn_s_barrier();

  auto kcbody = [&](auto oddc, int kc) {
    constexpr bool ODD = decltype(oddc)::value;
    const u16* xb = ODD ? &Xlds[1][0] : &Xlds[0][0];
    const u16* xbn = ODD ? &Xlds[0][0] : &Xlds[1][0];
#pragma unroll
    for (int tap = 0; tap < 9; ++tap) {
      const int CU_ = ((ODD ? 1 : 0) + tap) & 1;   // frags(s) slot (const-folded)
      const int NX_ = CU_ ^ 1;
      __builtin_amdgcn_sched_barrier(0);
      // --- issue W(s+3) into buf tap%3 (vacated by frags(s), read last step) ---
      {
        int ntap = (tap + 3 > 8) ? (tap - 6) : (tap + 3);
        int nkc = (tap >= 6) ? (kc + 1) : kc;   // kc=31 tail: in-ws garbage, dead
        u16* wd = (tap % 3 == 0) ? wdst0 : ((tap % 3 == 1) ? wdst1 : wdst2);
        gl2lds16(wsrc + (size_t)ntap * ((size_t)O << 10) + (nkc << 5), wd);
      }
      if (tap == 0) {  // stage X(kc+1) into other parity buffer
        if (ODD) { gl2lds16(xsrc0 + ((kc + 1) << 5), xdA0); gl2lds16(xsrc1 + ((kc + 1) << 5), xdA1); }
        else     { gl2lds16(xsrc0 + ((kc + 1) << 5), xdB0); gl2lds16(xsrc1 + ((kc + 1) << 5), xdB1); }
      }
      // --- ds_read frags for step s+1 (buffers published at barrier(s-1)) ---
      {
        const int ptap = (tap == 8) ? 0 : tap + 1;
        const u16* bwbn = ((tap + 1) % 3 == 0) ? bwb0
                        : (((tap + 1) % 3 == 1) ? bwb1 : bwb2);
#pragma unroll
        for (int nf = 0; nf < 4; ++nf) fw[NX_][nf] = *(const bf16x8*)(bwbn + (nf << 9));
        const int pdr = ptap / 3 - 1, pdc = ptap % 3 - 1;
        const int pdpo = (((pdr << 4) + pdc) << 5) + xsz[pdc + 1];
        const u16* xrd = (tap == 8) ? xbn : xb;
#pragma unroll
        for (int mf = 0; mf < 4; ++mf) {
          int rr = (wm << 2) + mf + pdr;
          bool v = ((unsigned)rr < 16u) & ((unsigned)(lr + pdc) < 16u);
          int off = v ? (pb[mf] + pdpo) : zoff;
          fa[NX_][mf] = *(const bf16x8*)(xrd + off);
        }
      }
      // --- MFMA step s (all operands in registers) ---
#pragma unroll
      for (int mf = 0; mf < 4; ++mf)
#pragma unroll
        for (int nf = 0; nf < 4; ++nf)
          acc[mf][nf] = __builtin_amdgcn_mfma_f32_16x16x32_bf16(fa[CU_][mf], fw[CU_][nf], acc[mf][nf], 0, 0, 0);
      // --- waits: own frag reads done (WAR safety), W(s+2) landed ---
      asm volatile("s_waitcnt lgkmcnt(0)" ::: "memory");
      if (tap < 2) asm volatile("s_waitcnt vmcnt(3)" ::: "memory");
      else         asm volatile("s_waitcnt vmcnt(1)" ::: "memory");
      __builtin_amdgcn_s_barrier();
    }
  };

#pragma unroll 1
  for (int kc2 = 0; kc2 < 16; ++kc2) {
    kcbody(BC<false>{}, 2 * kc2);
    kcbody(BC<true>{}, 2 * kc2 + 1);
  }

  // ---- epilogue: per-wave LDS transpose -> vectorized swizzled stores ----
  __syncthreads();   // drain outstanding prefetch; LDS reusable as scratch
  float bv[4];
#pragma unroll
  for (int nf = 0; nf < 4; ++nf) bv[nf] = bias[o0 + (wn << 6) + (nf << 4) + lr];
  u16* scr = ((u16*)Xlds) + w * 1152;   // per-wave 16 rows x 72 u16
  int rr2 = l >> 2;                     // 4 lanes per row
  int kq = l & 3;
#pragma unroll
  for (int mf = 0; mf < 4; ++mf) {
#pragma unroll
    for (int r = 0; r < 4; ++r) {
      int rr = (lq << 2) + r;
#pragma unroll
      for (int nf = 0; nf < 4; ++nf) {
        float vv = acc[mf][nf][r] + bv[nf];
        scr[rr * 72 + (nf << 4) + lr] = f2bf(vv > 0.f ? vv : 0.f);
      }
    }
    asm volatile("s_waitcnt lgkmcnt(0)" ::: "memory");
    __builtin_amdgcn_sched_barrier(0);
    int p = (wm << 6) + (mf << 4) + rr2;
    int sp = (p >> 1) & 3;
    size_t rbase = (size_t)((b << 8) + p) * O + (size_t)(o0 + (wn << 6));
#pragma unroll
    for (int j = 0; j < 2; ++j) {
      int k = (j << 2) | kq;             // stored chunk (monotone per group)
      int kl = (j << 2) | (kq ^ sp);     // logical chunk held at stored slot k
      uint4 v = *(const uint4*)(scr + rr2 * 72 + (kl << 3));
      *(uint4*)(Out + rbase + (k << 3)) = v;
    }
    asm volatile("s_waitcnt lgkmcnt(0)" ::: "memory");
    __builtin_amdgcn_sched_barrier(0);
  }
}

// ---------------------------------------------------------------------------
// Kernel 6: cls head. score[b][c] = mean_p relu(dot(out2T[b][p], Wc[c*256+p])),
// softmax over c. X2 rows swizzled: read stored chunks MONOTONICALLY (coalesced)
// and permute the WEIGHT chunk index instead (w reads are per-lane scattered
// rows anyway, so the permutation is free).
__global__ __launch_bounds__(256) void k_cls(const u16* __restrict__ X2,
                                             const float* __restrict__ Wc,
                                             float* __restrict__ out) {
  int b = blockIdx.x, p = threadIdx.x;
  int s = (p >> 1) & 3;
  const uint4* xv = (const uint4*)(X2 + (((size_t)(b << 8) + p) << 9));
  const float4* w0 = (const float4*)(Wc + ((size_t)p << 9));
  const float4* w1 = (const float4*)(Wc + ((size_t)(256 + p) << 9));
  float a0 = 0.f, a1 = 0.f;
#pragma unroll 4
  for (int i = 0; i < 64; ++i) {
    uint4 u = xv[i];                      // monotonic stored chunk
    int il = (i & ~3) | ((i & 3) ^ s);    // logical chunk held at stored slot i
    float x0 = bf2f((u16)(u.x & 0xffffu)), x1 = bf2f((u16)(u.x >> 16));
    float x2 = bf2f((u16)(u.y & 0xffffu)), x3 = bf2f((u16)(u.y >> 16));
    float x4 = bf2f((u16)(u.z & 0xffffu)), x5 = bf2f((u16)(u.z >> 16));
    float x6 = bf2f((u16)(u.w & 0xffffu)), x7 = bf2f((u16)(u.w >> 16));
    float4 wa = w0[il * 2], wb = w0[il * 2 + 1];
    a0 += x0 * wa.x + x1 * wa.y + x2 * wa.z + x3 * wa.w +
          x4 * wb.x + x5 * wb.y + x6 * wb.z + x7 * wb.w;
    float4 wc4 = w1[il * 2], wd = w1[il * 2 + 1];
    a1 += x0 * wc4.x + x1 * wc4.y + x2 * wc4.z + x3 * wc4.w +
          x4 * wd.x + x5 * wd.y + x6 * wd.z + x7 * wd.w;
  }
  a0 = fmaxf(a0, 0.f);
  a1 = fmaxf(a1, 0.f);
  __shared__ float r0[256], r1[256];
  r0[p] = a0; r1[p] = a1;
  for (int sdx = 128; sdx > 0; sdx >>= 1) {
    __syncthreads();
    if (p < sdx) { r0[p] += r0[p + sdx]; r1[p] += r1[p + sdx]; }
  }
  __syncthreads();
  if (p == 0) {
    float s0 = r0[0] * (1.f / 256.f), s1v = r1[0] * (1.f / 256.f);
    float m = fmaxf(s0, s1v);
    float e0 = expf(s0 - m), e1 = expf(s1v - m);
    float inv = 1.f / (e0 + e1);
    out[(b << 1) + 0] = e0 * inv;
    out[(b << 1) + 1] = e1 * inv;
  }
}

// ---------------------------------------------------------------------------
extern "C" void kernel_launch(void* const* d_in, const int* in_sizes, int n_in,
                              void* d_out, int out_size, void* d_ws, size_t ws_size,
                              hipStream_t stream) {
  const float* f1 = (const float*)d_in[0];
  const float* f2 = (const float*)d_in[1];
  const float* w1 = (const float*)d_in[2];
  const float* b1 = (const float*)d_in[3];
  const float* w2 = (const float*)d_in[4];
  const float* b2 = (const float*)d_in[5];
  const float* wc = (const float*)d_in[6];
  float* out = (float*)d_out;
  char* ws = (char*)d_ws;

  u16* featT = (u16*)(ws + 0);
  u16* out1T = (u16*)(ws + 134217728);
  u16* W1b   = (u16*)(ws + 268435456);
  u16* W2b   = (u16*)(ws + 287309824);
  float* s1  = (float*)(ws + 296747008);
  float* s2  = (float*)(ws + 297009152);
  u16* out2T = (u16*)(ws + 0);  // overlays featT (dead after conv1)

  k_norm<<<1024, 256, 0, stream>>>(f1, f2, featT, s1, s2);
  k_wconv<<<1024, 256, 0, stream>>>(w1, W1b, 1024, 1024);
  k_wconv<<<512, 256, 0, stream>>>(w2, W2b, 512, 1024);
  k_corr<<<1024, 256, 0, stream>>>(featT, s1, s2, out);
  k_conv<1024, 3><<<2048, 512, 0, stream>>>(featT, W1b, b1, out1T);
  k_conv<512, 2><<<1024, 512, 0, stream>>>(out1T, W2b, b2, out2T);
  k_cls<<<256, 256, 0, stream>>>(out2T, wc, out);
}